// Round 2
// baseline (678.260 us; speedup 1.0000x reference)
//
#include <hip/hip_runtime.h>
#include <hip/hip_bf16.h>

#define B_ 32
#define S_ 4096
#define H_ 512
#define M_ (B_ * S_)   // 131072
#define L_ 2

typedef __bf16 bf16;
typedef bf16 bf16x8 __attribute__((ext_vector_type(8)));
typedef bf16 bf16x4 __attribute__((ext_vector_type(4)));
typedef float floatx4 __attribute__((ext_vector_type(4)));

__device__ inline bf16 f2b(float f) { return (bf16)f; }

__device__ inline float fast_tanh(float x) {
    float xc = fminf(15.0f, fmaxf(-15.0f, x));
    float e = __expf(2.0f * xc);
    return (e - 1.0f) * __builtin_amdgcn_rcpf(e + 1.0f);
}

// ---------------- kernel 0: convert W (H,H) fp32 -> bf16, same layout ----------------
__global__ __launch_bounds__(256) void convert_W(const float* __restrict__ W,
                                                 bf16* __restrict__ Wb) {
    int i = blockIdx.x * 256 + threadIdx.x;      // float4 index, total H*H/4
    float4 w = ((const float4*)W)[i];
    bf16x4 p = { f2b(w.x), f2b(w.y), f2b(w.z), f2b(w.w) };
    *(bf16x4*)(Wb + (size_t)i * 4) = p;
}

// ---------------- kernel 1: fused scores ----------------
// scores[m] = sum_n tanh((out @ W^T)[m,n] + b[n] + hlast[batch,n]) * v[n]
//
// Structure: A (64 rows x 512 K) staged ONCE in LDS (bf16, XOR-swizzled 16B
// blocks, 64 KB -> 2 blocks/CU). ZERO barriers in the K-loop: W B-fragments
// are gathered directly from global (L2-resident, 512 KB bf16) into VGPRs.
// 4 waves split by N (no m-split -> no W duplication). Per wave: 4 m-tiles x
// 4 n-tiles = 16 MFMA per K-step, fully unrolled K=16 steps -> compiler
// pipelines global loads with fine-grained vmcnt.
#define MT 64

__global__ __launch_bounds__(256, 2) void scores_kernel(
    const float* __restrict__ outT,   // (M, 512)
    const bf16*  __restrict__ Wb,     // (512, 512) row-major (o, h)
    const float* __restrict__ bias,   // (512)
    const float* __restrict__ hidden, // (L, B, 512)
    const float* __restrict__ v,      // (512)
    float* __restrict__ scores)       // (M)
{
    __shared__ bf16 Alds[MT * 512];   // 65536 B exactly -> 2 blocks/CU

    const int tid  = threadIdx.x;
    const int wave = tid >> 6;
    const int lane = tid & 63;
    const int q    = lane >> 4;     // quad 0..3
    const int l16  = lane & 15;

    const int m0    = blockIdx.x * MT;
    const int batch = m0 >> 12;      // m0 / S_

    // ---- stage A: 64 rows x 512 fp32 -> bf16 LDS, 16B-block XOR swizzle.
    // Block j of row r stored at byte r*1024 + 16*(j ^ (r&7)).
    {
        const float4* src = (const float4*)(outT + (size_t)m0 * H_);
        #pragma unroll
        for (int it = 0; it < 16; ++it) {
            int idx = it * 256 + tid;     // 16B-block index (8 bf16), 4096 total
            int r   = idx >> 6;           // 64 blocks per row
            int j   = idx & 63;
            float4 f0 = src[idx * 2];
            float4 f1 = src[idx * 2 + 1];
            bf16x8 p = { f2b(f0.x), f2b(f0.y), f2b(f0.z), f2b(f0.w),
                         f2b(f1.x), f2b(f1.y), f2b(f1.z), f2b(f1.w) };
            *(bf16x8*)&Alds[r * 512 + 8 * (j ^ (r & 7))] = p;
        }
    }
    __syncthreads();   // the ONLY barrier

    float score_acc[4][4];
    #pragma unroll
    for (int mt = 0; mt < 4; ++mt)
        #pragma unroll
        for (int r = 0; r < 4; ++r) score_acc[mt][r] = 0.0f;

    #pragma unroll 1
    for (int nb = 0; nb < 2; ++nb) {
        const int nbase = nb * 256 + wave * 64;   // wave's 64 n-cols this pass

        floatx4 acc[4][4];
        #pragma unroll
        for (int mt = 0; mt < 4; ++mt)
            #pragma unroll
            for (int nt = 0; nt < 4; ++nt)
                acc[mt][nt] = (floatx4){0.f, 0.f, 0.f, 0.f};

        #pragma unroll
        for (int kc = 0; kc < 16; ++kc) {
            bf16x8 bfrag[4], afrag[4];
            #pragma unroll
            for (int nt = 0; nt < 4; ++nt)
                bfrag[nt] = *(const bf16x8*)(Wb + (size_t)(nbase + nt * 16 + l16) * H_
                                             + kc * 32 + q * 8);
            const int blk = kc * 4 + q;
            #pragma unroll
            for (int mt = 0; mt < 4; ++mt) {
                int row = mt * 16 + l16;
                afrag[mt] = *(const bf16x8*)&Alds[row * 512 + 8 * (blk ^ (row & 7))];
            }
            #pragma unroll
            for (int mt = 0; mt < 4; ++mt)
                #pragma unroll
                for (int nt = 0; nt < 4; ++nt)
                    acc[mt][nt] = __builtin_amdgcn_mfma_f32_16x16x32_bf16(
                        afrag[mt], bfrag[nt], acc[mt][nt], 0, 0, 0);
        }

        // epilogue for this n-pass: tanh(acc + b + hlast) * v
        #pragma unroll
        for (int nt = 0; nt < 4; ++nt) {
            int n = nbase + nt * 16 + l16;
            float bias_n = bias[n] + hidden[(size_t)((L_ - 1) * B_ + batch) * H_ + n];
            float v_n = v[n];
            #pragma unroll
            for (int mt = 0; mt < 4; ++mt)
                #pragma unroll
                for (int r = 0; r < 4; ++r) {
                    float e = fast_tanh(acc[mt][nt][r] + bias_n);
                    score_acc[mt][r] += e * v_n;
                }
        }
    }

    // reduce partials across the 16 n-lanes of each quad; C/D row = q*4 + r
    #pragma unroll
    for (int mt = 0; mt < 4; ++mt)
        #pragma unroll
        for (int r = 0; r < 4; ++r) {
            float s = score_acc[mt][r];
            s += __shfl_xor(s, 1);
            s += __shfl_xor(s, 2);
            s += __shfl_xor(s, 4);
            s += __shfl_xor(s, 8);
            if (l16 == 0)
                atomicAdd(&scores[m0 + mt * 16 + q * 4 + r], s);
        }
}

// ---------------- kernel 2: softmax over S per batch ----------------
__global__ __launch_bounds__(256) void softmax_kernel(const float* __restrict__ scores,
                                                      float* __restrict__ attn) {
    __shared__ float red[4];
    int b = blockIdx.x, tid = threadIdx.x;
    const float* row = scores + (size_t)b * S_;
    float vals[16];
    float mx = -3.4e38f;
    #pragma unroll
    for (int i = 0; i < 16; ++i) { vals[i] = row[i * 256 + tid]; mx = fmaxf(mx, vals[i]); }
    #pragma unroll
    for (int off = 32; off >= 1; off >>= 1) mx = fmaxf(mx, __shfl_xor(mx, off));
    if ((tid & 63) == 0) red[tid >> 6] = mx;
    __syncthreads();
    mx = fmaxf(fmaxf(red[0], red[1]), fmaxf(red[2], red[3]));
    __syncthreads();
    float sum = 0.f;
    #pragma unroll
    for (int i = 0; i < 16; ++i) { vals[i] = __expf(vals[i] - mx); sum += vals[i]; }
    #pragma unroll
    for (int off = 32; off >= 1; off >>= 1) sum += __shfl_xor(sum, off);
    if ((tid & 63) == 0) red[tid >> 6] = sum;
    __syncthreads();
    float inv = 1.0f / (red[0] + red[1] + red[2] + red[3]);
    #pragma unroll
    for (int i = 0; i < 16; ++i) attn[(size_t)b * S_ + i * 256 + tid] = vals[i] * inv;
}

// ---------------- kernel 3: context[b,h] = sum_s attn[b,s] * out[b,s,h] ----------------
// float4 loads: lane owns h-float4 = tid&127; 2 s-groups per block.
#define SCHUNK 256
__global__ __launch_bounds__(256, 2) void context_kernel(const float* __restrict__ outT,
                                                         const float* __restrict__ attn,
                                                         float* __restrict__ ctx) {
    int b   = blockIdx.y;
    int s0  = blockIdx.x * SCHUNK;
    int tid = threadIdx.x;
    int h4  = tid & 127;          // float4 index within H (128 per row)
    int sg  = tid >> 7;           // 0..1

    floatx4 acc = {0.f, 0.f, 0.f, 0.f};
    const floatx4* base = (const floatx4*)(outT + ((size_t)b * S_ + s0) * H_);
    const float*   arow = attn + (size_t)b * S_ + s0;

    #pragma unroll 4
    for (int s = sg; s < SCHUNK; s += 2) {
        float a   = arow[s];
        floatx4 o = base[(size_t)s * 128 + h4];
        acc += a * o;
    }
    float* c = ctx + (size_t)b * H_ + h4 * 4;
    atomicAdd(c + 0, acc[0]);
    atomicAdd(c + 1, acc[1]);
    atomicAdd(c + 2, acc[2]);
    atomicAdd(c + 3, acc[3]);
}

extern "C" void kernel_launch(void* const* d_in, const int* in_sizes, int n_in,
                              void* d_out, int out_size, void* d_ws, size_t ws_size,
                              hipStream_t stream) {
    const float* outT   = (const float*)d_in[0];  // (B,S,H)
    const float* hidden = (const float*)d_in[1];  // (L,B,H)
    const float* W      = (const float*)d_in[2];  // (H,H)
    const float* bias   = (const float*)d_in[3];  // (H)
    const float* v      = (const float*)d_in[4];  // (H)

    float* ctx    = (float*)d_out;                // (B,H)
    float* attn   = (float*)d_out + B_ * H_;      // (B,S)
    float* scores = (float*)d_ws;                 // M floats (512 KB)
    bf16*  Wb     = (bf16*)((char*)d_ws + (size_t)M_ * sizeof(float)); // 512 KB

    hipMemsetAsync(scores, 0, (size_t)M_ * sizeof(float), stream);
    hipMemsetAsync(ctx, 0, (size_t)B_ * H_ * sizeof(float), stream);

    convert_W<<<H_ * H_ / 4 / 256, 256, 0, stream>>>(W, Wb);
    scores_kernel<<<M_ / MT, 256, 0, stream>>>(outT, Wb, bias, hidden, v, scores);
    softmax_kernel<<<B_, 256, 0, stream>>>(scores, attn);
    context_kernel<<<dim3(S_ / SCHUNK, B_), 256, 0, stream>>>(outT, attn, ctx);
}

// Round 3
// 527.030 us; speedup vs baseline: 1.2869x; 1.2869x over previous
//
#include <hip/hip_runtime.h>
#include <hip/hip_bf16.h>

#define B_ 32
#define S_ 4096
#define H_ 512
#define M_ (B_ * S_)   // 131072
#define L_ 2

typedef __bf16 bf16;
typedef bf16 bf16x8 __attribute__((ext_vector_type(8)));
typedef bf16 bf16x4 __attribute__((ext_vector_type(4)));
typedef float floatx4 __attribute__((ext_vector_type(4)));

__device__ inline bf16 f2b(float f) { return (bf16)f; }

__device__ inline float fast_tanh(float x) {
    float xc = fminf(15.0f, fmaxf(-15.0f, x));
    float e = __expf(2.0f * xc);
    return (e - 1.0f) * __builtin_amdgcn_rcpf(e + 1.0f);
}

// ---------------- kernel 0: convert W (H,H) fp32 -> bf16, same layout ----------------
__global__ __launch_bounds__(256) void convert_W(const float* __restrict__ W,
                                                 bf16* __restrict__ Wb) {
    int i = blockIdx.x * 256 + threadIdx.x;      // float4 index, total H*H/4
    float4 w = ((const float4*)W)[i];
    bf16x4 p = { f2b(w.x), f2b(w.y), f2b(w.z), f2b(w.w) };
    *(bf16x4*)(Wb + (size_t)i * 4) = p;
}

// ---------------- kernel 1: fused scores ----------------
// scores[m] = sum_n tanh((out @ W^T)[m,n] + b[n] + hlast[batch,n]) * v[n]
//
// A (64 x 512) staged once in LDS (bf16, XOR-swizzled 16B blocks, 64 KB ->
// 2 blocks/CU). Zero barriers in the K-loop; W B-fragments gathered from
// global (L2-resident) into an explicit DEPTH-1 ping-pong register buffer
// (K=64 rounds: prefetch 8 b128 while 32 MFMAs consume the other buffer).
// Bounded live set: bbuf 64 + afrag 16 + acc 64(AGPR) + misc -> no spills.
#define MT 64

__global__ __launch_bounds__(256, 2) void scores_kernel(
    const float* __restrict__ outT,   // (M, 512)
    const bf16*  __restrict__ Wb,     // (512, 512) row-major (o, h) = (n, k)
    const float* __restrict__ bias,   // (512)
    const float* __restrict__ hidden, // (L, B, 512)
    const float* __restrict__ v,      // (512)
    float* __restrict__ scores)       // (M)
{
    __shared__ bf16 Alds[MT * 512];   // 65536 B exactly -> 2 blocks/CU

    const int tid  = threadIdx.x;
    const int wave = tid >> 6;
    const int lane = tid & 63;
    const int q    = lane >> 4;     // quad 0..3
    const int l16  = lane & 15;
    const int l7   = l16 & 7;

    const int m0    = blockIdx.x * MT;
    const int batch = m0 >> 12;      // m0 / S_

    // ---- stage A: 64 rows x 512 fp32 -> bf16 LDS, 16B-block XOR swizzle.
    // Block j of row r stored at element r*512 + 8*(j ^ (r&7)).
    {
        const float4* src = (const float4*)(outT + (size_t)m0 * H_);
        #pragma unroll 4
        for (int it = 0; it < 16; ++it) {
            int idx = it * 256 + tid;     // 16B-block index (8 bf16), 4096 total
            int r   = idx >> 6;           // 64 blocks per row
            int j   = idx & 63;
            float4 f0 = src[idx * 2];
            float4 f1 = src[idx * 2 + 1];
            bf16x8 p = { f2b(f0.x), f2b(f0.y), f2b(f0.z), f2b(f0.w),
                         f2b(f1.x), f2b(f1.y), f2b(f1.z), f2b(f1.w) };
            *(bf16x8*)&Alds[r * 512 + 8 * (j ^ (r & 7))] = p;
        }
    }
    __syncthreads();

    float score_acc[4][4];
    #pragma unroll
    for (int mt = 0; mt < 4; ++mt)
        #pragma unroll
        for (int r = 0; r < 4; ++r) score_acc[mt][r] = 0.0f;

    #pragma unroll 1
    for (int nb = 0; nb < 2; ++nb) {
        const int nbase = nb * 256 + wave * 64;   // wave's 64 n-cols this pass
        // per-lane W base: row (nbase + l16), k-offset q*8
        const bf16* wbase = Wb + (size_t)(nbase + l16) * H_ + q * 8;

        floatx4 acc[4][4];
        #pragma unroll
        for (int mt = 0; mt < 4; ++mt)
            #pragma unroll
            for (int nt = 0; nt < 4; ++nt)
                acc[mt][nt] = (floatx4){0.f, 0.f, 0.f, 0.f};

        // ping-pong B-fragment buffer: [buf][kstep-within-round][nt]
        bf16x8 bbuf[2][2][4];
        #pragma unroll
        for (int ks = 0; ks < 2; ++ks)
            #pragma unroll
            for (int nt = 0; nt < 4; ++nt)
                bbuf[0][ks][nt] = *(const bf16x8*)(wbase + nt * (16 * H_) + ks * 32);

        #pragma unroll 2
        for (int kc2 = 0; kc2 < 8; ++kc2) {
            const int cur = kc2 & 1, nxt = cur ^ 1;
            const int knext = (kc2 * 2 + 2) & 15;   // wraps harmlessly on last round
            #pragma unroll
            for (int ks = 0; ks < 2; ++ks)
                #pragma unroll
                for (int nt = 0; nt < 4; ++nt)
                    bbuf[nxt][ks][nt] =
                        *(const bf16x8*)(wbase + nt * (16 * H_) + (knext + ks) * 32);

            #pragma unroll
            for (int ks = 0; ks < 2; ++ks) {
                const int kstep = kc2 * 2 + ks;
                bf16x8 afrag[4];
                #pragma unroll
                for (int mt = 0; mt < 4; ++mt)
                    afrag[mt] = *(const bf16x8*)
                        &Alds[(mt * 16 + l16) * 512 + 8 * ((kstep * 4 + q) ^ l7)];
                #pragma unroll
                for (int mt = 0; mt < 4; ++mt)
                    #pragma unroll
                    for (int nt = 0; nt < 4; ++nt)
                        acc[mt][nt] = __builtin_amdgcn_mfma_f32_16x16x32_bf16(
                            afrag[mt], bbuf[cur][ks][nt], acc[mt][nt], 0, 0, 0);
            }
        }

        // epilogue for this n-pass: tanh(acc + b + hlast) * v
        const float* hlast = hidden + (size_t)((L_ - 1) * B_ + batch) * H_;
        #pragma unroll
        for (int nt = 0; nt < 4; ++nt) {
            int n = nbase + nt * 16 + l16;
            float bias_n = bias[n] + hlast[n];
            float v_n = v[n];
            #pragma unroll
            for (int mt = 0; mt < 4; ++mt)
                #pragma unroll
                for (int r = 0; r < 4; ++r) {
                    float e = fast_tanh(acc[mt][nt][r] + bias_n);
                    score_acc[mt][r] += e * v_n;
                }
        }
    }

    // ---- cross-wave score reduction through LDS (reuses Alds; no atomics).
    // Within each quad: sum over the 16 n-lanes; C/D row = q*4 + r.
    __syncthreads();   // all waves done reading Alds
    float* sred = (float*)Alds;      // 4 waves x 64 rows
    #pragma unroll
    for (int mt = 0; mt < 4; ++mt)
        #pragma unroll
        for (int r = 0; r < 4; ++r) {
            float s = score_acc[mt][r];
            s += __shfl_xor(s, 1);
            s += __shfl_xor(s, 2);
            s += __shfl_xor(s, 4);
            s += __shfl_xor(s, 8);
            if (l16 == 0) sred[wave * 64 + mt * 16 + q * 4 + r] = s;
        }
    __syncthreads();
    if (tid < 64)
        scores[m0 + tid] = (sred[tid] + sred[64 + tid]) + (sred[128 + tid] + sred[192 + tid]);
}

// ---------------- kernel 2: softmax over S per batch ----------------
__global__ __launch_bounds__(256) void softmax_kernel(const float* __restrict__ scores,
                                                      float* __restrict__ attn) {
    __shared__ float red[4];
    int b = blockIdx.x, tid = threadIdx.x;
    const float* row = scores + (size_t)b * S_;
    float vals[16];
    float mx = -3.4e38f;
    #pragma unroll
    for (int i = 0; i < 16; ++i) { vals[i] = row[i * 256 + tid]; mx = fmaxf(mx, vals[i]); }
    #pragma unroll
    for (int off = 32; off >= 1; off >>= 1) mx = fmaxf(mx, __shfl_xor(mx, off));
    if ((tid & 63) == 0) red[tid >> 6] = mx;
    __syncthreads();
    mx = fmaxf(fmaxf(red[0], red[1]), fmaxf(red[2], red[3]));
    __syncthreads();
    float sum = 0.f;
    #pragma unroll
    for (int i = 0; i < 16; ++i) { vals[i] = __expf(vals[i] - mx); sum += vals[i]; }
    #pragma unroll
    for (int off = 32; off >= 1; off >>= 1) sum += __shfl_xor(sum, off);
    if ((tid & 63) == 0) red[tid >> 6] = sum;
    __syncthreads();
    float inv = 1.0f / (red[0] + red[1] + red[2] + red[3]);
    #pragma unroll
    for (int i = 0; i < 16; ++i) attn[(size_t)b * S_ + i * 256 + tid] = vals[i] * inv;
}

// ---------------- kernel 3: context[b,h] = sum_s attn[b,s] * out[b,s,h] ----------------
// 1024 blocks (4/CU). Lane owns one float4 of H; 2 s-groups of 64; 4
// independent accumulators -> 4 16B loads in flight per lane.
#define SCHUNK 128
__global__ __launch_bounds__(256) void context_kernel(const float* __restrict__ outT,
                                                      const float* __restrict__ attn,
                                                      float* __restrict__ ctx) {
    int b   = blockIdx.y;
    int s0  = blockIdx.x * SCHUNK;
    int tid = threadIdx.x;
    int h4  = tid & 127;          // float4 index within H (128 per row)
    int sg  = tid >> 7;           // 0..1 -> s-subchunk of 64

    const floatx4* bp   = (const floatx4*)(outT + ((size_t)b * S_ + s0 + sg * 64) * H_) + h4;
    const float*   arow = attn + (size_t)b * S_ + s0 + sg * 64;

    floatx4 a0 = {0.f,0.f,0.f,0.f}, a1 = a0, a2 = a0, a3 = a0;
    #pragma unroll 2
    for (int j = 0; j < 64; j += 4) {
        float w0 = arow[j + 0], w1 = arow[j + 1], w2 = arow[j + 2], w3 = arow[j + 3];
        a0 += w0 * bp[(size_t)(j + 0) * 128];
        a1 += w1 * bp[(size_t)(j + 1) * 128];
        a2 += w2 * bp[(size_t)(j + 2) * 128];
        a3 += w3 * bp[(size_t)(j + 3) * 128];
    }
    floatx4 a = (a0 + a1) + (a2 + a3);
    float* c = ctx + (size_t)b * H_ + h4 * 4;
    atomicAdd(c + 0, a[0]);
    atomicAdd(c + 1, a[1]);
    atomicAdd(c + 2, a[2]);
    atomicAdd(c + 3, a[3]);
}

extern "C" void kernel_launch(void* const* d_in, const int* in_sizes, int n_in,
                              void* d_out, int out_size, void* d_ws, size_t ws_size,
                              hipStream_t stream) {
    const float* outT   = (const float*)d_in[0];  // (B,S,H)
    const float* hidden = (const float*)d_in[1];  // (L,B,H)
    const float* W      = (const float*)d_in[2];  // (H,H)
    const float* bias   = (const float*)d_in[3];  // (H)
    const float* v      = (const float*)d_in[4];  // (H)

    float* ctx    = (float*)d_out;                // (B,H)
    float* attn   = (float*)d_out + B_ * H_;      // (B,S)
    float* scores = (float*)d_ws;                 // M floats (512 KB)
    bf16*  Wb     = (bf16*)((char*)d_ws + (size_t)M_ * sizeof(float)); // 512 KB

    hipMemsetAsync(ctx, 0, (size_t)B_ * H_ * sizeof(float), stream);

    convert_W<<<H_ * H_ / 4 / 256, 256, 0, stream>>>(W, Wb);
    scores_kernel<<<M_ / MT, 256, 0, stream>>>(outT, Wb, bias, hidden, v, scores);
    softmax_kernel<<<B_, 256, 0, stream>>>(scores, attn);
    context_kernel<<<dim3(S_ / SCHUNK, B_), 256, 0, stream>>>(outT, attn, ctx);
}

// Round 4
// 468.032 us; speedup vs baseline: 1.4492x; 1.1261x over previous
//
#include <hip/hip_runtime.h>
#include <hip/hip_bf16.h>

#define B_ 32
#define S_ 4096
#define H_ 512
#define M_ (B_ * S_)   // 131072
#define L_ 2

typedef __bf16 bf16;
typedef bf16 bf16x8 __attribute__((ext_vector_type(8)));
typedef float floatx4 __attribute__((ext_vector_type(4)));
typedef float floatx16 __attribute__((ext_vector_type(16)));

__device__ inline bf16 f2b(float f) { return (bf16)f; }

__device__ inline float fast_tanh(float x) {
    float xc = fminf(15.0f, fmaxf(-15.0f, x));
    float e = __expf(2.0f * xc);
    return (e - 1.0f) * __builtin_amdgcn_rcpf(e + 1.0f);
}

// ---------------- kernel 0: W (H,H) fp32 -> bf16 MFMA-fragment-major ----------------
// Fragment (nt, ks) = B-operand of mfma_32x32x16 for n-rows [nt*32, nt*32+32),
// k [ks*16, ks*16+16). Stored as 64 lanes x 16B contiguous (1 KB):
// lane l holds W[nt*32 + (l&31)][ks*16 + (l>>5)*8 .. +8).
// Wf index: ((nt*32 + ks)*64 + l)*8 elems. One bfrag load = 1 contiguous KB.
__global__ __launch_bounds__(256) void convert_Wfrag(const float* __restrict__ W,
                                                     bf16* __restrict__ Wf) {
    int gid  = blockIdx.x * 256 + threadIdx.x;   // 0..32767
    int lane = gid & 63;
    int ks   = (gid >> 6) & 31;
    int nt   = gid >> 11;                        // 0..15
    int row  = nt * 32 + (lane & 31);
    int col  = ks * 16 + (lane >> 5) * 8;
    const float* src = W + (size_t)row * H_ + col;
    floatx4 f0 = *(const floatx4*)src;
    floatx4 f1 = *(const floatx4*)(src + 4);
    bf16x8 p = { f2b(f0[0]), f2b(f0[1]), f2b(f0[2]), f2b(f0[3]),
                 f2b(f1[0]), f2b(f1[1]), f2b(f1[2]), f2b(f1[3]) };
    *(bf16x8*)(Wf + (size_t)gid * 8) = p;
}

// ---------------- kernel 1: fused scores ----------------
// scores[m] = sum_n tanh((out @ W^T)[m,n] + b[n] + hlast[batch,n]) * v[n]
// Block: 256 thr (4 waves), M-tile 64, full N=512 (wave w owns n [w*128,w*128+128)).
// A staged ONCE in LDS, fragment-major with kstep rotation (64 KB -> 2 blocks/CU).
// B frags stream from L2 (Wf, coalesced 1KB loads) through a depth-4 register
// ring. Zero barriers in the K-loop. MFMA 32x32x16: 8/kstep/wave, 32 ksteps.
#define MT 64

__global__ __launch_bounds__(256, 2) void scores_kernel(
    const float* __restrict__ outT,   // (M, 512)
    const bf16*  __restrict__ Wf,     // fragment-major W (512 KB)
    const float* __restrict__ bias,   // (512)
    const float* __restrict__ hidden, // (L, B, 512)
    const float* __restrict__ v,      // (512)
    float* __restrict__ scores)       // (M)
{
    __shared__ bf16 Alds[MT * 512];   // 64 KB, fragment-major

    const int tid  = threadIdx.x;
    const int wave = tid >> 6;
    const int lane = tid & 63;
    const int l31  = lane & 31;
    const int half = lane >> 5;       // 0..1

    const int m0    = blockIdx.x * MT;
    const int batch = m0 >> 12;       // m0 / S_

    // ---- stage A: 64 rows x 512 fp32 -> bf16 fragment-major LDS.
    // A-frag (mt, ks): lane l holds A[mt*32 + (l&31)][ks*16 + (l>>5)*8 ..+8)
    // at slot = (l>>5)*32 + ((l&31) + ks)&31  (rotation kills write conflicts).
    {
        const floatx4* src = (const floatx4*)(outT + (size_t)m0 * H_);
        #pragma unroll 4
        for (int it = 0; it < 16; ++it) {
            int idx = it * 256 + tid;     // 16B-block index: r = row, j = k-block
            int r   = idx >> 6;
            int j   = idx & 63;
            floatx4 f0 = __builtin_nontemporal_load(src + idx * 2);
            floatx4 f1 = __builtin_nontemporal_load(src + idx * 2 + 1);
            bf16x8 p = { f2b(f0[0]), f2b(f0[1]), f2b(f0[2]), f2b(f0[3]),
                         f2b(f1[0]), f2b(f1[1]), f2b(f1[2]), f2b(f1[3]) };
            int frag = (r >> 5) * 32 + (j >> 1);
            int slot = (j & 1) * 32 + ((r + (j >> 1)) & 31);
            *(bf16x8*)&Alds[frag * 512 + slot * 8] = p;
        }
    }
    __syncthreads();

    // per-lane Wf base: frag(nt, ks) at wf + nt*16384 + ks*512
    const bf16* wf = Wf + (size_t)(wave * 4) * 32 * 512 + lane * 8;

    floatx16 acc[2][4];
    #pragma unroll
    for (int mt = 0; mt < 2; ++mt)
        #pragma unroll
        for (int nt = 0; nt < 4; ++nt)
            acc[mt][nt] = (floatx16)(0.0f);

    // depth-4 B prefetch ring
    bf16x8 bbuf[4][4];
    #pragma unroll
    for (int p = 0; p < 4; ++p)
        #pragma unroll
        for (int nt = 0; nt < 4; ++nt)
            bbuf[p][nt] = *(const bf16x8*)(wf + nt * 16384 + p * 512);

    #pragma unroll 4
    for (int ks = 0; ks < 32; ++ks) {
        const int cur = ks & 3;
        bf16x8 afrag[2];
        const int rot = (l31 + ks) & 31;
        #pragma unroll
        for (int mt = 0; mt < 2; ++mt)
            afrag[mt] = *(const bf16x8*)&Alds[(mt * 32 + ks) * 512 + (half * 32 + rot) * 8];
        #pragma unroll
        for (int mt = 0; mt < 2; ++mt)
            #pragma unroll
            for (int nt = 0; nt < 4; ++nt)
                acc[mt][nt] = __builtin_amdgcn_mfma_f32_32x32x16_bf16(
                    afrag[mt], bbuf[cur][nt], acc[mt][nt], 0, 0, 0);
        if (ks < 28) {
            #pragma unroll
            for (int nt = 0; nt < 4; ++nt)
                bbuf[cur][nt] = *(const bf16x8*)(wf + nt * 16384 + (ks + 4) * 512);
        }
    }

    // ---- epilogue: tanh(acc + b + hlast) * v, sum over n.
    // C/D of 32x32: col = lane&31, row = (reg&3) + 8*(reg>>2) + 4*(lane>>5).
    const float* hlast = hidden + (size_t)((L_ - 1) * B_ + batch) * H_;
    float part[2][16];
    #pragma unroll
    for (int mt = 0; mt < 2; ++mt)
        #pragma unroll
        for (int rg = 0; rg < 16; ++rg) part[mt][rg] = 0.0f;

    #pragma unroll
    for (int nt = 0; nt < 4; ++nt) {
        int n = wave * 128 + nt * 32 + l31;
        float bn = bias[n] + hlast[n];
        float vn = v[n];
        #pragma unroll
        for (int mt = 0; mt < 2; ++mt)
            #pragma unroll
            for (int rg = 0; rg < 16; ++rg)
                part[mt][rg] += fast_tanh(acc[mt][nt][rg] + bn) * vn;
    }

    // reduce over the 32 cols (lanes within each 32-half); rows of the two
    // halves are disjoint (offset +4), so no cross-half combine needed.
    __syncthreads();                 // done reading Alds; reuse as scratch
    float* sred = (float*)Alds;      // 4 waves x 64 rows
    #pragma unroll
    for (int mt = 0; mt < 2; ++mt)
        #pragma unroll
        for (int rg = 0; rg < 16; ++rg) {
            float s = part[mt][rg];
            s += __shfl_xor(s, 1);
            s += __shfl_xor(s, 2);
            s += __shfl_xor(s, 4);
            s += __shfl_xor(s, 8);
            s += __shfl_xor(s, 16);
            if (l31 == 0) {
                int row = (rg & 3) + 8 * (rg >> 2) + 4 * half;
                sred[wave * 64 + mt * 32 + row] = s;
            }
        }
    __syncthreads();
    if (tid < 64)
        scores[m0 + tid] = (sred[tid] + sred[64 + tid]) + (sred[128 + tid] + sred[192 + tid]);
}

// ---------------- kernel 2: softmax over S per batch ----------------
__global__ __launch_bounds__(256) void softmax_kernel(const float* __restrict__ scores,
                                                      float* __restrict__ attn) {
    __shared__ float red[4];
    int b = blockIdx.x, tid = threadIdx.x;
    const float* row = scores + (size_t)b * S_;
    float vals[16];
    float mx = -3.4e38f;
    #pragma unroll
    for (int i = 0; i < 16; ++i) { vals[i] = row[i * 256 + tid]; mx = fmaxf(mx, vals[i]); }
    #pragma unroll
    for (int off = 32; off >= 1; off >>= 1) mx = fmaxf(mx, __shfl_xor(mx, off));
    if ((tid & 63) == 0) red[tid >> 6] = mx;
    __syncthreads();
    mx = fmaxf(fmaxf(red[0], red[1]), fmaxf(red[2], red[3]));
    __syncthreads();
    float sum = 0.f;
    #pragma unroll
    for (int i = 0; i < 16; ++i) { vals[i] = __expf(vals[i] - mx); sum += vals[i]; }
    #pragma unroll
    for (int off = 32; off >= 1; off >>= 1) sum += __shfl_xor(sum, off);
    if ((tid & 63) == 0) red[tid >> 6] = sum;
    __syncthreads();
    float inv = 1.0f / (red[0] + red[1] + red[2] + red[3]);
    #pragma unroll
    for (int i = 0; i < 16; ++i) attn[(size_t)b * S_ + i * 256 + tid] = vals[i] * inv;
}

// ---------------- kernel 3a: context partials (no atomics) ----------------
// partial[b][sb][h] = sum_{s in chunk} attn[b,s] * out[b,s,h]; 512 blocks.
#define CS 256
__global__ __launch_bounds__(256) void context_partial(const float* __restrict__ outT,
                                                       const float* __restrict__ attn,
                                                       float* __restrict__ partial) {
    __shared__ float red[2][512];
    int b  = blockIdx.y;
    int sb = blockIdx.x;                 // 0..15
    int tid = threadIdx.x;
    int h4 = tid & 127;                  // float4 col
    int sg = tid >> 7;                   // 0..1 -> 128-row half

    const floatx4* bp = (const floatx4*)(outT + ((size_t)b * S_ + sb * CS + sg * 128) * H_) + h4;
    const float*   ar = attn + (size_t)b * S_ + sb * CS + sg * 128;

    floatx4 a0 = (floatx4)(0.0f), a1 = a0, a2 = a0, a3 = a0;
    #pragma unroll 2
    for (int j = 0; j < 128; j += 4) {
        float w0 = ar[j + 0], w1 = ar[j + 1], w2 = ar[j + 2], w3 = ar[j + 3];
        a0 += w0 * __builtin_nontemporal_load(bp + (size_t)(j + 0) * 128);
        a1 += w1 * __builtin_nontemporal_load(bp + (size_t)(j + 1) * 128);
        a2 += w2 * __builtin_nontemporal_load(bp + (size_t)(j + 2) * 128);
        a3 += w3 * __builtin_nontemporal_load(bp + (size_t)(j + 3) * 128);
    }
    floatx4 a = (a0 + a1) + (a2 + a3);
    *(floatx4*)&red[sg][h4 * 4] = a;
    __syncthreads();
    if (tid < 128) {
        floatx4 r = *(floatx4*)&red[0][tid * 4] + *(floatx4*)&red[1][tid * 4];
        *(floatx4*)&partial[((size_t)b * 16 + sb) * H_ + tid * 4] = r;
    }
}

// ---------------- kernel 3b: reduce partials -> ctx ----------------
__global__ __launch_bounds__(256) void context_final(const float* __restrict__ partial,
                                                     float* __restrict__ ctx) {
    int gid = blockIdx.x * 256 + threadIdx.x;   // b*512 + h
    int b = gid >> 9, h = gid & 511;
    float s = 0.f;
    #pragma unroll
    for (int k = 0; k < 16; ++k) s += partial[((size_t)b * 16 + k) * H_ + h];
    ctx[gid] = s;
}

extern "C" void kernel_launch(void* const* d_in, const int* in_sizes, int n_in,
                              void* d_out, int out_size, void* d_ws, size_t ws_size,
                              hipStream_t stream) {
    const float* outT   = (const float*)d_in[0];  // (B,S,H)
    const float* hidden = (const float*)d_in[1];  // (L,B,H)
    const float* W      = (const float*)d_in[2];  // (H,H)
    const float* bias   = (const float*)d_in[3];  // (H)
    const float* v      = (const float*)d_in[4];  // (H)

    float* ctx    = (float*)d_out;                // (B,H)
    float* attn   = (float*)d_out + B_ * H_;      // (B,S)
    float* scores  = (float*)d_ws;                                  // 512 KB
    bf16*  Wf      = (bf16*)((char*)d_ws + (size_t)M_ * 4);         // 512 KB
    float* partial = (float*)((char*)d_ws + (size_t)M_ * 4 + H_ * H_ * 2); // 1 MB

    convert_Wfrag<<<128, 256, 0, stream>>>(W, Wf);
    scores_kernel<<<M_ / MT, 256, 0, stream>>>(outT, Wf, bias, hidden, v, scores);
    softmax_kernel<<<B_, 256, 0, stream>>>(scores, attn);
    context_partial<<<dim3(S_ / CS, B_), 256, 0, stream>>>(outT, attn, partial);
    context_final<<<B_ * H_ / 256, 256, 0, stream>>>(partial, ctx);
}

// Round 5
// 457.906 us; speedup vs baseline: 1.4812x; 1.0221x over previous
//
#include <hip/hip_runtime.h>
#include <hip/hip_bf16.h>

#define B_ 32
#define S_ 4096
#define H_ 512
#define M_ (B_ * S_)   // 131072
#define L_ 2

typedef __bf16 bf16;
typedef bf16 bf16x8 __attribute__((ext_vector_type(8)));
typedef float floatx4 __attribute__((ext_vector_type(4)));
typedef float floatx16 __attribute__((ext_vector_type(16)));

__device__ inline bf16 f2b(float f) { return (bf16)f; }

__device__ inline float fast_tanh(float x) {
    float xc = fminf(15.0f, fmaxf(-15.0f, x));
    float e = __expf(2.0f * xc);
    return (e - 1.0f) * __builtin_amdgcn_rcpf(e + 1.0f);
}

// ---------------- kernel 0: W (H,H) fp32 -> bf16 MFMA-fragment-major ----------------
// Fragment (nt, ks) = B-operand of mfma_32x32x16 for n-rows [nt*32, nt*32+32),
// k [ks*16, ks*16+16). Stored as 64 lanes x 16B contiguous (1 KB):
// lane l holds W[nt*32 + (l&31)][ks*16 + (l>>5)*8 .. +8).
__global__ __launch_bounds__(256) void convert_Wfrag(const float* __restrict__ W,
                                                     bf16* __restrict__ Wf) {
    int gid  = blockIdx.x * 256 + threadIdx.x;   // 0..32767
    int lane = gid & 63;
    int ks   = (gid >> 6) & 31;
    int nt   = gid >> 11;                        // 0..15
    int row  = nt * 32 + (lane & 31);
    int col  = ks * 16 + (lane >> 5) * 8;
    const float* src = W + (size_t)row * H_ + col;
    floatx4 f0 = *(const floatx4*)src;
    floatx4 f1 = *(const floatx4*)(src + 4);
    bf16x8 p = { f2b(f0[0]), f2b(f0[1]), f2b(f0[2]), f2b(f0[3]),
                 f2b(f1[0]), f2b(f1[1]), f2b(f1[2]), f2b(f1[3]) };
    *(bf16x8*)(Wf + (size_t)gid * 8) = p;
}

// ---------------- kernel 1: fused scores ----------------
// scores[m] = sum_n tanh((out @ W^T)[m,n] + b[n] + hlast[batch,n]) * v[n]
// 4 waves, M-tile 64, wave w owns n in [w*128, w*128+128).
// A staged once in LDS fragment-major (rotation-swizzled), 64 KB -> 2 blk/CU.
// K-loop: FULLY unrolled 32 ksteps, zero barriers, depth-2 A register
// ping-pong (LDS latency hidden), depth-4 B register ring from L2.
#define MT 64

__global__ __launch_bounds__(256, 2) void scores_kernel(
    const float* __restrict__ outT,   // (M, 512)
    const bf16*  __restrict__ Wf,     // fragment-major W (512 KB)
    const float* __restrict__ bias,   // (512)
    const float* __restrict__ hidden, // (L, B, 512)
    const float* __restrict__ v,      // (512)
    float* __restrict__ scores)       // (M)
{
    __shared__ bf16 Alds[MT * 512];   // 64 KB, fragment-major

    const int tid  = threadIdx.x;
    const int wave = tid >> 6;
    const int lane = tid & 63;
    const int l31  = lane & 31;
    const int half = lane >> 5;       // 0..1

    const int m0    = blockIdx.x * MT;
    const int batch = m0 >> 12;       // m0 / S_

    // ---- stage A: 64 rows x 512 fp32 -> bf16 fragment-major LDS.
    // A-frag (mt, ks): lane l holds A[mt*32 + (l&31)][ks*16 + (l>>5)*8 ..+8)
    // at slot = (l>>5)*32 + ((l&31) + ks)&31  (rotation kills write conflicts).
    {
        const floatx4* src = (const floatx4*)(outT + (size_t)m0 * H_);
        #pragma unroll 4
        for (int it = 0; it < 16; ++it) {
            int idx = it * 256 + tid;     // 16B-block index: r = row, j = k-block
            int r   = idx >> 6;
            int j   = idx & 63;
            floatx4 f0 = __builtin_nontemporal_load(src + idx * 2);
            floatx4 f1 = __builtin_nontemporal_load(src + idx * 2 + 1);
            bf16x8 p = { f2b(f0[0]), f2b(f0[1]), f2b(f0[2]), f2b(f0[3]),
                         f2b(f1[0]), f2b(f1[1]), f2b(f1[2]), f2b(f1[3]) };
            int frag = (r >> 5) * 32 + (j >> 1);
            int slot = (j & 1) * 32 + ((r + (j >> 1)) & 31);
            *(bf16x8*)&Alds[frag * 512 + slot * 8] = p;
        }
    }
    __syncthreads();

    // per-lane Wf base: frag(nt, ks) at wf + nt*16384 + ks*512
    const bf16* wf = Wf + (size_t)(wave * 4) * 32 * 512 + lane * 8;

    floatx16 acc[2][4];
    #pragma unroll
    for (int mt = 0; mt < 2; ++mt)
        #pragma unroll
        for (int nt = 0; nt < 4; ++nt)
            acc[mt][nt] = (floatx16)(0.0f);

    // depth-4 B ring (slot = ks & 3), depth-2 A ping-pong (slot = ks & 1)
    bf16x8 bb[4][4];
    bf16x8 aa[2][2];
    #pragma unroll
    for (int p = 0; p < 4; ++p)
        #pragma unroll
        for (int nt = 0; nt < 4; ++nt)
            bb[p][nt] = *(const bf16x8*)(wf + nt * 16384 + p * 512);
    #pragma unroll
    for (int mt = 0; mt < 2; ++mt)
        aa[0][mt] = *(const bf16x8*)
            &Alds[(mt * 32 + 0) * 512 + (half * 32 + (l31 & 31)) * 8];

    #pragma unroll
    for (int ks = 0; ks < 32; ++ks) {
        const int cur = ks & 3;
        const int ap  = ks & 1;
        // A-prefetch for ks+1 FIRST: ds_read latency hidden behind the MFMAs
        if (ks < 31) {
            const int rot = (l31 + ks + 1) & 31;
            #pragma unroll
            for (int mt = 0; mt < 2; ++mt)
                aa[ap ^ 1][mt] = *(const bf16x8*)
                    &Alds[(mt * 32 + ks + 1) * 512 + (half * 32 + rot) * 8];
        }
        #pragma unroll
        for (int mt = 0; mt < 2; ++mt)
            #pragma unroll
            for (int nt = 0; nt < 4; ++nt)
                acc[mt][nt] = __builtin_amdgcn_mfma_f32_32x32x16_bf16(
                    aa[ap][mt], bb[cur][nt], acc[mt][nt], 0, 0, 0);
        // B-prefetch for ks+4 into the slot just consumed
        if (ks < 28) {
            #pragma unroll
            for (int nt = 0; nt < 4; ++nt)
                bb[cur][nt] = *(const bf16x8*)(wf + nt * 16384 + (ks + 4) * 512);
        }
    }

    // ---- epilogue: tanh(acc + b + hlast) * v, sum over n.
    // C/D of 32x32: col = lane&31, row = (reg&3) + 8*(reg>>2) + 4*(lane>>5).
    const float* hlast = hidden + (size_t)((L_ - 1) * B_ + batch) * H_;
    float part[2][16];
    #pragma unroll
    for (int mt = 0; mt < 2; ++mt)
        #pragma unroll
        for (int rg = 0; rg < 16; ++rg) part[mt][rg] = 0.0f;

    #pragma unroll
    for (int nt = 0; nt < 4; ++nt) {
        int n = wave * 128 + nt * 32 + l31;
        float bn = bias[n] + hlast[n];
        float vn = v[n];
        #pragma unroll
        for (int mt = 0; mt < 2; ++mt)
            #pragma unroll
            for (int rg = 0; rg < 16; ++rg)
                part[mt][rg] += fast_tanh(acc[mt][nt][rg] + bn) * vn;
    }

    // reduce over the 32 cols (lanes within each 32-half); rows of the two
    // halves are disjoint (offset +4), so no cross-half combine needed.
    __syncthreads();                 // done reading Alds; reuse as scratch
    float* sred = (float*)Alds;      // 4 waves x 64 rows
    #pragma unroll
    for (int mt = 0; mt < 2; ++mt)
        #pragma unroll
        for (int rg = 0; rg < 16; ++rg) {
            float s = part[mt][rg];
            s += __shfl_xor(s, 1);
            s += __shfl_xor(s, 2);
            s += __shfl_xor(s, 4);
            s += __shfl_xor(s, 8);
            s += __shfl_xor(s, 16);
            if (l31 == 0) {
                int row = (rg & 3) + 8 * (rg >> 2) + 4 * half;
                sred[wave * 64 + mt * 32 + row] = s;
            }
        }
    __syncthreads();
    if (tid < 64)
        scores[m0 + tid] = (sred[tid] + sred[64 + tid]) + (sred[128 + tid] + sred[192 + tid]);
}

// ---------------- kernel 2: softmax over S per batch ----------------
__global__ __launch_bounds__(256) void softmax_kernel(const float* __restrict__ scores,
                                                      float* __restrict__ attn) {
    __shared__ float red[4];
    int b = blockIdx.x, tid = threadIdx.x;
    const float* row = scores + (size_t)b * S_;
    float vals[16];
    float mx = -3.4e38f;
    #pragma unroll
    for (int i = 0; i < 16; ++i) { vals[i] = row[i * 256 + tid]; mx = fmaxf(mx, vals[i]); }
    #pragma unroll
    for (int off = 32; off >= 1; off >>= 1) mx = fmaxf(mx, __shfl_xor(mx, off));
    if ((tid & 63) == 0) red[tid >> 6] = mx;
    __syncthreads();
    mx = fmaxf(fmaxf(red[0], red[1]), fmaxf(red[2], red[3]));
    __syncthreads();
    float sum = 0.f;
    #pragma unroll
    for (int i = 0; i < 16; ++i) { vals[i] = __expf(vals[i] - mx); sum += vals[i]; }
    #pragma unroll
    for (int off = 32; off >= 1; off >>= 1) sum += __shfl_xor(sum, off);
    if ((tid & 63) == 0) red[tid >> 6] = sum;
    __syncthreads();
    float inv = 1.0f / (red[0] + red[1] + red[2] + red[3]);
    #pragma unroll
    for (int i = 0; i < 16; ++i) attn[(size_t)b * S_ + i * 256 + tid] = vals[i] * inv;
}

// ---------------- kernel 3a: context partials (no atomics) ----------------
// partial[b][sb][h] = sum_{s in chunk} attn[b,s] * out[b,s,h]; 512 blocks.
#define CS 256
__global__ __launch_bounds__(256) void context_partial(const float* __restrict__ outT,
                                                       const float* __restrict__ attn,
                                                       float* __restrict__ partial) {
    __shared__ float red[2][512];
    int b  = blockIdx.y;
    int sb = blockIdx.x;                 // 0..15
    int tid = threadIdx.x;
    int h4 = tid & 127;                  // float4 col
    int sg = tid >> 7;                   // 0..1 -> 128-row half

    const floatx4* bp = (const floatx4*)(outT + ((size_t)b * S_ + sb * CS + sg * 128) * H_) + h4;
    const float*   ar = attn + (size_t)b * S_ + sb * CS + sg * 128;

    floatx4 a0 = (floatx4)(0.0f), a1 = a0, a2 = a0, a3 = a0;
    #pragma unroll 2
    for (int j = 0; j < 128; j += 4) {
        float w0 = ar[j + 0], w1 = ar[j + 1], w2 = ar[j + 2], w3 = ar[j + 3];
        a0 += w0 * __builtin_nontemporal_load(bp + (size_t)(j + 0) * 128);
        a1 += w1 * __builtin_nontemporal_load(bp + (size_t)(j + 1) * 128);
        a2 += w2 * __builtin_nontemporal_load(bp + (size_t)(j + 2) * 128);
        a3 += w3 * __builtin_nontemporal_load(bp + (size_t)(j + 3) * 128);
    }
    floatx4 a = (a0 + a1) + (a2 + a3);
    *(floatx4*)&red[sg][h4 * 4] = a;
    __syncthreads();
    if (tid < 128) {
        floatx4 r = *(floatx4*)&red[0][tid * 4] + *(floatx4*)&red[1][tid * 4];
        *(floatx4*)&partial[((size_t)b * 16 + sb) * H_ + tid * 4] = r;
    }
}

// ---------------- kernel 3b: reduce partials -> ctx ----------------
__global__ __launch_bounds__(256) void context_final(const float* __restrict__ partial,
                                                     float* __restrict__ ctx) {
    int gid = blockIdx.x * 256 + threadIdx.x;   // b*512 + h
    int b = gid >> 9, h = gid & 511;
    float s = 0.f;
    #pragma unroll
    for (int k = 0; k < 16; ++k) s += partial[((size_t)b * 16 + k) * H_ + h];
    ctx[gid] = s;
}

extern "C" void kernel_launch(void* const* d_in, const int* in_sizes, int n_in,
                              void* d_out, int out_size, void* d_ws, size_t ws_size,
                              hipStream_t stream) {
    const float* outT   = (const float*)d_in[0];  // (B,S,H)
    const float* hidden = (const float*)d_in[1];  // (L,B,H)
    const float* W      = (const float*)d_in[2];  // (H,H)
    const float* bias   = (const float*)d_in[3];  // (H)
    const float* v      = (const float*)d_in[4];  // (H)

    float* ctx    = (float*)d_out;                // (B,H)
    float* attn   = (float*)d_out + B_ * H_;      // (B,S)
    float* scores  = (float*)d_ws;                                  // 512 KB
    bf16*  Wf      = (bf16*)((char*)d_ws + (size_t)M_ * 4);         // 512 KB
    float* partial = (float*)((char*)d_ws + (size_t)M_ * 4 + H_ * H_ * 2); // 1 MB

    convert_Wfrag<<<128, 256, 0, stream>>>(W, Wf);
    scores_kernel<<<M_ / MT, 256, 0, stream>>>(outT, Wf, bias, hidden, v, scores);
    softmax_kernel<<<B_, 256, 0, stream>>>(scores, attn);
    context_partial<<<dim3(S_ / CS, B_), 256, 0, stream>>>(outT, attn, partial);
    context_final<<<B_ * H_ / 256, 256, 0, stream>>>(partial, ctx);
}